// Round 2
// baseline (1155.803 us; speedup 1.0000x reference)
//
#include <hip/hip_runtime.h>
#include <hip/hip_bf16.h>
#include <float.h>
#include <math.h>

typedef __hip_bfloat16 bf16;

__device__ __forceinline__ float bf2f(bf16 v){ return __bfloat162float(v); }
__device__ __forceinline__ void stv(float* p, float v){ *p = v; }
__device__ __forceinline__ void stv(bf16* p, float v){ *p = __float2bfloat16(v); }
__device__ __forceinline__ float nanfix(float v){
  if (v != v) return 0.f;
  return fminf(fmaxf(v, -FLT_MAX), FLT_MAX);
}

// ---------------- sorting / misc ----------------
__global__ void k_deg(const int* __restrict__ tgt, int* __restrict__ deg, int E){
  int e = blockIdx.x*blockDim.x + threadIdx.x;
  if (e < E) atomicAdd(&deg[tgt[e]], 1);
}

__global__ void k_scan(const int* __restrict__ deg, int* __restrict__ offs, int N){
  __shared__ int sm[1024];
  __shared__ int carry_s;
  int tid = threadIdx.x;
  if (tid == 0){ offs[0] = 0; carry_s = 0; }
  __syncthreads();
  for (int base = 0; base < N; base += 1024){
    int i = base + tid;
    int v = (i < N) ? deg[i] : 0;
    sm[tid] = v; __syncthreads();
    for (int off = 1; off < 1024; off <<= 1){
      int t = (tid >= off) ? sm[tid-off] : 0;
      __syncthreads();
      sm[tid] += t;
      __syncthreads();
    }
    int carry = carry_s;
    if (i < N) offs[i+1] = carry + sm[tid];
    __syncthreads();
    if (tid == 0) carry_s += sm[1023];
    __syncthreads();
  }
}

__global__ void k_scatter(const int* __restrict__ src, const int* __restrict__ tgt,
                          const int* __restrict__ offs, int* __restrict__ cnt,
                          int* __restrict__ ssrc, int E){
  int e = blockIdx.x*blockDim.x + threadIdx.x;
  if (e < E){
    int t = tgt[e];
    int pos = offs[t] + atomicAdd(&cnt[t], 1);
    ssrc[pos] = src[e];
  }
}

// ---------------- weight repacks (float32 inputs) ----------------
// Wpq[c, t*F+f] = preW[t,c,f]; Wpq[c, NC + t*F+f] = preW[t,K+c,f]; bias first half only
__global__ void k_repack_pq(const float* __restrict__ preW, const float* __restrict__ preB,
                            float* __restrict__ Wpq, float* __restrict__ bpq,
                            int K, int F, int T){
  int NC = T*F;
  int total = K*2*NC;
  int idx = blockIdx.x*blockDim.x + threadIdx.x;
  if (idx < total){
    int c = idx/(2*NC); int col = idx%(2*NC);
    int half = col/NC; int j = col%NC; int t = j/F; int f = j%F;
    Wpq[idx] = preW[(t*2*K + half*K + c)*F + f];
  }
  if (idx < 2*NC) bpq[idx] = (idx < NC) ? preB[idx] : 0.f;
}

// Wx[c*NC+j] = postW[t,c,f] ; Wagg[((t*4F+cc)*3+s)*F+f] = postW[t, KX + s*4F + cc, f]
__global__ void k_repack_post(const float* __restrict__ postW, const float* __restrict__ postB,
                              float* __restrict__ Wx, float* __restrict__ Wagg,
                              float* __restrict__ bpost, int KX, int F, int T){
  int NC = T*F; int KP = KX + 12*F;
  int totalx = KX*NC; int totala = T*4*F*3*F;
  int idx = blockIdx.x*blockDim.x + threadIdx.x;
  if (idx < totalx){
    int c = idx/NC; int j = idx%NC; int t = j/F; int f = j%F;
    Wx[idx] = postW[(t*KP + c)*F + f];
  } else if (idx < totalx + totala){
    int i2 = idx - totalx;
    int f = i2 % F; int r = i2 / F; int s = r % 3; r /= 3;
    int cc = r % (4*F); int t = r / (4*F);
    Wagg[i2] = postW[(t*KP + KX + s*4*F + cc)*F + f];
  }
  if (idx < NC) bpost[idx] = postB[idx];
}

// ---------------- generic 64x64 tiled GEMM: out[N,NC] = A[N,K] @ W[K,NC] + bias ----------------
template<typename TO>
__global__ __launch_bounds__(256) void k_gemm(const float* __restrict__ A, int N, int K,
                       const float* __restrict__ W, int NC,
                       const float* __restrict__ bias, TO* __restrict__ out){
  __shared__ float As[16][68];
  __shared__ float Ws[16][64];
  int tid = threadIdx.x;
  int n0 = blockIdx.x*64, j0 = blockIdx.y*64;
  int ty = tid/16, tx = tid%16;
  int a_n = tid/4, a_k = (tid%4)*4;
  int w_k = tid/16, w_j = (tid%16)*4;
  float acc[4][4] = {};
  for (int k0 = 0; k0 < K; k0 += 16){
    int n = n0 + a_n;
    float4 av = make_float4(0.f,0.f,0.f,0.f);
    if (n < N) av = *(const float4*)(A + (size_t)n*K + k0 + a_k);
    As[a_k+0][a_n]=av.x; As[a_k+1][a_n]=av.y; As[a_k+2][a_n]=av.z; As[a_k+3][a_n]=av.w;
    float4 wv = *(const float4*)(W + (size_t)(k0+w_k)*NC + j0 + w_j);
    *(float4*)&Ws[w_k][w_j] = wv;
    __syncthreads();
    #pragma unroll
    for (int kk = 0; kk < 16; kk++){
      float a[4], b[4];
      #pragma unroll
      for (int i=0;i<4;i++) a[i] = As[kk][ty*4+i];
      #pragma unroll
      for (int jj=0;jj<4;jj++) b[jj] = Ws[kk][tx*4+jj];
      #pragma unroll
      for (int i=0;i<4;i++)
        #pragma unroll
        for (int jj=0;jj<4;jj++) acc[i][jj] += a[i]*b[jj];
    }
    __syncthreads();
  }
  #pragma unroll
  for (int i=0;i<4;i++){
    int n = n0 + ty*4 + i;
    if (n < N){
      #pragma unroll
      for (int jj=0;jj<4;jj++){
        int col = j0 + tx*4 + jj;
        stv(&out[(size_t)n*NC + col], acc[i][jj] + bias[col]);
      }
    }
  }
}

// ---------------- per-node PNA aggregation ----------------
// PQ: [N, 2*NC] bf16 (P = tgt-half incl bias, Q = src-half). agg out: [N, T*4F] fp32.
template<int NC, int F>
__global__ void k_agg(const bf16* __restrict__ PQ,
                      const int* __restrict__ ssrc, const int* __restrict__ offs,
                      const float* __restrict__ avgp,
                      float* __restrict__ agg, float* __restrict__ scal, int N){
  int n = blockIdx.x; if (n >= N) return;
  int tid = threadIdx.x;
  float p = bf2f(PQ[(size_t)n*2*NC + tid]);
  int s0 = offs[n], s1 = offs[n+1];
  float sum = 0.f, sq = 0.f, mn = FLT_MAX, mx = -FLT_MAX;
  for (int i = s0; i < s1; i++){
    int s = ssrc[i];
    float m = p + bf2f(PQ[(size_t)s*2*NC + NC + tid]);
    sum += m; sq += m*m; mn = fminf(mn, m); mx = fmaxf(mx, m);
  }
  int deg = s1 - s0;
  float degc = fmaxf((float)deg, 1.f);
  float mean = sum/degc;
  float var = fmaxf(sq/degc - mean*mean, 0.f);
  float sd = sqrtf(var + 1e-5f);
  if (deg == 0){ mn = 0.f; mx = 0.f; }
  int t = tid / F, ff = tid % F;
  size_t base = (size_t)n*4*NC + t*4*F;
  agg[base + ff]       = mean;
  agg[base + F  + ff]  = mn;
  agg[base + 2*F + ff] = mx;
  agg[base + 3*F + ff] = sd;
  if (tid == 0){
    float dlog = logf(degc + 1.f);
    float avg = *avgp;
    scal[2*n]   = dlog/avg;
    scal[2*n+1] = avg/dlog;
  }
}

// ---------------- post-tower GEMM with PNA scalers (block-diagonal over towers) ----------------
// grid (ceil(N/16), T); block 256 = F cols x (256/F) node-subsets
template<int F, int KX>
__global__ __launch_bounds__(256) void k_post(const float* __restrict__ X,
      const float* __restrict__ agg,
      const float* __restrict__ Wx, const float* __restrict__ Wagg,
      const float* __restrict__ bias, const float* __restrict__ scal,
      float* __restrict__ out, int N, int T){
  const int TN = 16, SUBS = 256/F, MY = TN/SUBS;
  const int K4F = 4*F;
  __shared__ float lx[KX*TN];
  __shared__ float la[K4F*TN];
  int t0 = blockIdx.y; int NC = T*F;
  int n0 = blockIdx.x*TN;
  int tid = threadIdx.x;
  for (int idx = tid; idx < KX*TN; idx += 256){
    int c = idx/TN, k = idx%TN; int n = n0 + k;
    lx[idx] = (n < N) ? X[(size_t)n*KX + c] : 0.f;
  }
  for (int idx = tid; idx < K4F*TN; idx += 256){
    int cc = idx/TN, k = idx%TN; int n = n0 + k;
    la[idx] = (n < N) ? agg[(size_t)n*4*NC + t0*K4F + cc] : 0.f;
  }
  __syncthreads();
  int f = tid % F; int sub = tid / F; int kbase = sub*MY;
  int j = t0*F + f;
  float acc0[MY] = {}, acc1[MY] = {}, acc2[MY] = {};
  for (int c = 0; c < KX; c++){
    float w = Wx[(size_t)c*NC + j];
    const float* xp = &lx[c*TN + kbase];
    #pragma unroll
    for (int m = 0; m < MY; m++) acc0[m] += xp[m]*w;
  }
  for (int cc = 0; cc < K4F; cc++){
    const float* wp = Wagg + ((size_t)(t0*K4F + cc)*3)*F + f;
    float w0 = wp[0], w1 = wp[F], w2 = wp[2*F];
    const float* ap = &la[cc*TN + kbase];
    #pragma unroll
    for (int m = 0; m < MY; m++){
      float a = ap[m];
      acc0[m] += a*w0; acc1[m] += a*w1; acc2[m] += a*w2;
    }
  }
  float bj = bias[j];
  #pragma unroll
  for (int m = 0; m < MY; m++){
    int n = n0 + kbase + m;
    if (n < N) out[(size_t)n*NC + j] = bj + acc0[m] + scal[2*n]*acc1[m] + scal[2*n+1]*acc2[m];
  }
}

// ---------------- batch norm ----------------
template<int C>
__global__ void k_bn_stats(const float* __restrict__ h, float* __restrict__ stats, int N){
  int c = threadIdx.x;
  int n0 = blockIdx.x*256;
  int n1 = min(n0 + 256, N);
  float s = 0.f, q = 0.f;
  for (int n = n0; n < n1; n++){
    float v = nanfix(h[(size_t)n*C + c]);
    s += v; q += v*v;
  }
  atomicAdd(&stats[c], s);
  atomicAdd(&stats[C + c], q);
}

template<typename TO, int C>
__global__ void k_bn_apply(const float* __restrict__ h, const float* __restrict__ stats,
     const float* __restrict__ g, const float* __restrict__ b,
     TO* __restrict__ out, int N){
  int idx = blockIdx.x*blockDim.x + threadIdx.x;
  if (idx >= N*C) return;
  int c = idx % C;
  float fn = (float)N;
  float m = stats[c]/fn;
  float var = fmaxf(stats[C + c]/fn - m*m, 0.f);
  float inv = rsqrtf(var + 1e-5f);
  float v = nanfix(h[idx]);
  float r = g[c]*(v - m)*inv + b[c];
  stv(&out[idx], fmaxf(r, 0.f));
}

static inline int cdiv(int a, int b){ return (a + b - 1)/b; }

extern "C" void kernel_launch(void* const* d_in, const int* in_sizes, int n_in,
                              void* d_out, int out_size, void* d_ws, size_t ws_size,
                              hipStream_t stream){
  const int IN = 128, HID = 256, T = 4, F1 = 64, F2 = 32;
  const int N = in_sizes[0]/IN;
  const int E = in_sizes[1]/2;

  const float* x      = (const float*)d_in[0];
  const int*   ei     = (const int*)  d_in[1];
  const int*   srcE   = ei;
  const int*   tgtE   = ei + E;
  const float* avgp   = (const float*)d_in[2];
  const float* pre1W  = (const float*)d_in[3];
  const float* pre1b  = (const float*)d_in[4];
  const float* post1W = (const float*)d_in[5];
  const float* post1b = (const float*)d_in[6];
  const float* lin1W  = (const float*)d_in[7];   // [T*F1, HID] row-major: use directly
  const float* lin1b  = (const float*)d_in[8];
  const float* bn1g   = (const float*)d_in[9];
  const float* bn1b   = (const float*)d_in[10];
  const float* pre2W  = (const float*)d_in[11];
  const float* pre2b  = (const float*)d_in[12];
  const float* post2W = (const float*)d_in[13];
  const float* post2b = (const float*)d_in[14];
  const float* lin2W  = (const float*)d_in[15];  // [T*F2, 128] row-major: use directly
  const float* lin2b  = (const float*)d_in[16];
  const float* bn2g   = (const float*)d_in[17];
  const float* bn2b   = (const float*)d_in[18];

  // ---- workspace carve ----
  char* w = (char*)d_ws;
  auto alloc = [&](size_t bytes)->void*{
    void* p = (void*)w; w += (bytes + 255) & ~(size_t)255; return p;
  };
  float* Wpq1   = (float*)alloc((size_t)IN*2*T*F1*4);   float* bpq1 = (float*)alloc(2*T*F1*4);
  float* Wx1    = (float*)alloc((size_t)IN*T*F1*4);
  float* Wagg1  = (float*)alloc((size_t)T*4*F1*3*F1*4); float* bpost1 = (float*)alloc(T*F1*4);
  float* Wpq2   = (float*)alloc((size_t)HID*2*T*F2*4);  float* bpq2 = (float*)alloc(2*T*F2*4);
  float* Wx2    = (float*)alloc((size_t)HID*T*F2*4);
  float* Wagg2  = (float*)alloc((size_t)T*4*F2*3*F2*4); float* bpost2 = (float*)alloc(T*F2*4);
  int* deg_i    = (int*)alloc((size_t)N*4);
  int* offs     = (int*)alloc((size_t)(N+1)*4);
  int* cnt      = (int*)alloc((size_t)N*4);
  int* ssrc     = (int*)alloc((size_t)E*4);
  bf16* PQ      = (bf16*)alloc((size_t)N*512*2);
  float* aggb   = (float*)alloc((size_t)N*1024*4);
  float* scal   = (float*)alloc((size_t)N*2*4);
  float* postb  = (float*)alloc((size_t)N*256*4);
  float* hpre   = (float*)alloc((size_t)N*256*4);
  float* h1     = (float*)alloc((size_t)N*256*4);
  float* stats  = (float*)alloc(1024*4);   // [0..511] layer1, [512..1023] layer2

  // ---- zero accumulators ----
  hipMemsetAsync(deg_i, 0, (size_t)N*4, stream);
  hipMemsetAsync(cnt,   0, (size_t)N*4, stream);
  hipMemsetAsync(stats, 0, 1024*4, stream);

  // ---- repack weights ----
  k_repack_pq<<<cdiv(IN*2*T*F1,256),256,0,stream>>>(pre1W, pre1b, Wpq1, bpq1, IN, F1, T);
  k_repack_post<<<cdiv(IN*T*F1 + T*4*F1*3*F1,256),256,0,stream>>>(post1W, post1b, Wx1, Wagg1, bpost1, IN, F1, T);
  k_repack_pq<<<cdiv(HID*2*T*F2,256),256,0,stream>>>(pre2W, pre2b, Wpq2, bpq2, HID, F2, T);
  k_repack_post<<<cdiv(HID*T*F2 + T*4*F2*3*F2,256),256,0,stream>>>(post2W, post2b, Wx2, Wagg2, bpost2, HID, F2, T);

  // ---- counting sort of edges by target ----
  k_deg<<<cdiv(E,256),256,0,stream>>>(tgtE, deg_i, E);
  k_scan<<<1,1024,0,stream>>>(deg_i, offs, N);
  k_scatter<<<cdiv(E,256),256,0,stream>>>(srcE, tgtE, offs, cnt, ssrc, E);

  // ================= Layer 1 =================
  { dim3 g(cdiv(N,64), (2*T*F1)/64);
    k_gemm<bf16><<<g,256,0,stream>>>(x, N, IN, Wpq1, 2*T*F1, bpq1, PQ); }
  k_agg<256,64><<<N,256,0,stream>>>(PQ, ssrc, offs, avgp, aggb, scal, N);
  { dim3 g(cdiv(N,16), T);
    k_post<64,128><<<g,256,0,stream>>>(x, aggb, Wx1, Wagg1, bpost1, scal, postb, N, T); }
  { dim3 g(cdiv(N,64), HID/64);
    k_gemm<float><<<g,256,0,stream>>>(postb, N, T*F1, lin1W, HID, lin1b, hpre); }
  k_bn_stats<256><<<cdiv(N,256),256,0,stream>>>(hpre, stats, N);
  k_bn_apply<float,256><<<cdiv(N*256,256),256,0,stream>>>(hpre, stats, bn1g, bn1b, h1, N);

  // ================= Layer 2 =================
  { dim3 g(cdiv(N,64), (2*T*F2)/64);
    k_gemm<bf16><<<g,256,0,stream>>>(h1, N, HID, Wpq2, 2*T*F2, bpq2, PQ); }
  k_agg<128,32><<<N,128,0,stream>>>(PQ, ssrc, offs, avgp, aggb, scal, N);
  { dim3 g(cdiv(N,16), T);
    k_post<32,256><<<g,256,0,stream>>>(h1, aggb, Wx2, Wagg2, bpost2, scal, postb, N, T); }
  { dim3 g(cdiv(N,64), 128/64);
    k_gemm<float><<<g,256,0,stream>>>(postb, N, T*F2, lin2W, 128, lin2b, hpre); }
  k_bn_stats<128><<<cdiv(N,256),128,0,stream>>>(hpre, stats + 512, N);
  k_bn_apply<float,128><<<cdiv(N*128,256),256,0,stream>>>(hpre, stats + 512, bn2g, bn2b, (float*)d_out, N);
}